// Round 18
// baseline (1445.601 us; speedup 1.0000x reference)
//
#include <hip/hip_runtime.h>
#include <cstdint>

#define BB 256
#define TT 1000
#define DD 256
#define SS 10
#define HH 64
#define CC 100
// 2*log2(e): accumulate z2' = PRE*z so tanh(z) = 1 - 2/(exp2(z2')+1)
#define PRE 2.885390081777927f

typedef float f32x2 __attribute__((ext_vector_type(2)));
typedef float f32x4 __attribute__((ext_vector_type(4)));

__device__ __forceinline__ f32x2 lo2(f32x4 v) {
  return __builtin_shufflevector(v, v, 0, 1);
}
__device__ __forceinline__ f32x2 hi2(f32x4 v) {
  return __builtin_shufflevector(v, v, 2, 3);
}

// ---------------------------------------------------------------------------
// Producer wave (w=1,2,3): k-slice [KO, KO+4*KQ) of the D=256 dot.
// W-slice in registers (PRE-prescaled); x rows via wave-uniform f32x4 loads,
// double-buffered across c; partials into bias-pre-initialized buf rows via
// ds_add_f32. Publish: threadfence_block (drains this wave's ds_adds), then
// LANE 0 ONLY bumps prod_cnt[s] by 1  <-- R17 bug: all 64 lanes added,
// prod_cnt hit 64 after ONE wave and the consumer started 2 slices early.
// Pipeline rule: segment s writable only after rec_done[s-2].
// ---------------------------------------------------------------------------
template <int KQ, int KO>
__device__ __forceinline__ void proj_wave(
    const float* __restrict__ x, const float* __restrict__ W_ih,
    float (*__restrict__ buf)[CC][68], int* __restrict__ prod_cnt,
    int* __restrict__ rec_done, int b, int lane) {
  f32x4 Wk[KQ];
  for (int s = 0; s < SS; ++s) {
    const float* wrow = W_ih + ((size_t)s * HH + lane) * DD + KO;
#pragma unroll
    for (int q = 0; q < KQ; ++q) {
      f32x4 v = *(const f32x4*)(wrow + 4 * q);
      Wk[q] = (f32x4){PRE * v.x, PRE * v.y, PRE * v.z, PRE * v.w};
    }
    if (s >= 2) {
      while (__hip_atomic_load(&rec_done[s - 2], __ATOMIC_ACQUIRE,
                               __HIP_MEMORY_SCOPE_WORKGROUP) == 0)
        __builtin_amdgcn_s_sleep(1);
    }
    float(*dst)[68] = buf[s & 1];
    const float* xb0 = x + ((size_t)b * TT + (size_t)s * CC) * DD + KO;

    f32x4 xa[KQ], xb[KQ];
#pragma unroll
    for (int q = 0; q < KQ; ++q) xa[q] = *(const f32x4*)(xb0 + 4 * q);

    for (int c2 = 0; c2 < CC; c2 += 2) {
      const float* xr1 = xb0 + (size_t)(c2 + 1) * DD;
#pragma unroll
      for (int q = 0; q < KQ; ++q) xb[q] = *(const f32x4*)(xr1 + 4 * q);
      {
        f32x2 a0 = {0.f, 0.f}, a1 = {0.f, 0.f};
#pragma unroll
        for (int q = 0; q < KQ; ++q) {
          a0 = __builtin_elementwise_fma(lo2(Wk[q]), lo2(xa[q]), a0);
          a1 = __builtin_elementwise_fma(hi2(Wk[q]), hi2(xa[q]), a1);
        }
        const f32x2 t = a0 + a1;
        atomicAdd(&dst[c2][lane], t.x + t.y);  // ds_add_f32
      }
      if (c2 + 2 < CC) {
        const float* xr2 = xb0 + (size_t)(c2 + 2) * DD;
#pragma unroll
        for (int q = 0; q < KQ; ++q) xa[q] = *(const f32x4*)(xr2 + 4 * q);
      }
      {
        f32x2 a0 = {0.f, 0.f}, a1 = {0.f, 0.f};
#pragma unroll
        for (int q = 0; q < KQ; ++q) {
          a0 = __builtin_elementwise_fma(lo2(Wk[q]), lo2(xb[q]), a0);
          a1 = __builtin_elementwise_fma(hi2(Wk[q]), hi2(xb[q]), a1);
        }
        const f32x2 t = a0 + a1;
        atomicAdd(&dst[c2 + 1][lane], t.x + t.y);
      }
    }
    __threadfence_block();                  // drain this wave's ds_adds
    if (lane == 0) atomicAdd(&prod_cnt[s], 1);  // THE FIX: publish once
  }
}

// ---------------------------------------------------------------------------
// Fused kernel: 256 blocks x 4 waves = exactly 1 wave per SIMD (no slot
// sharing -- the R14 failure mode). Wave 0: R13-proven recurrence + head,
// xv from LDS. Waves 1-3: proj k-slices {88,88,80}. Sync: LDS flags +
// s_sleep spin, 2-segment pipeline depth; NO barriers in the main loop.
// buf[2][100][68]: row c of parity s&1 holds xp (bias-init + 3 ds_adds),
// overwritten in place by h at step c; head reads h rows; rec then refills
// parity rows with bias(s+2) before releasing them to the producers.
// ---------------------------------------------------------------------------
__global__ __launch_bounds__(256, 1) void fused_kernel(
    const float* __restrict__ x, const float* __restrict__ W_ih,
    const float* __restrict__ W_hh, const float* __restrict__ b_ih,
    const float* __restrict__ b_hh, const float* __restrict__ fc_w,
    const float* __restrict__ fc_b, float* __restrict__ y) {
  __shared__ float buf[2][CC][68];
  __shared__ float hrow[HH];
  __shared__ int prod_cnt[SS];
  __shared__ int rec_done[SS];
  const int b = blockIdx.x;
  const int tid = threadIdx.x;
  const int lane = tid & 63;
  const int w = tid >> 6;

  // ---- prologue: flags, handoff row, bias-init parities 0 and 1
  if (tid < SS) { prod_cnt[tid] = 0; rec_done[tid] = 0; }
  if (tid < HH) hrow[tid] = 0.f;
  {
    const float bias0 = PRE * (b_ih[0 * HH + lane] + b_hh[0 * HH + lane]);
    const float bias1 = PRE * (b_ih[1 * HH + lane] + b_hh[1 * HH + lane]);
    for (int c = w; c < CC; c += 4) {
      buf[0][c][lane] = bias0;
      buf[1][c][lane] = bias1;
    }
  }
  __syncthreads();  // the only block-wide barrier

  if (w == 0) {
    __builtin_amdgcn_s_setprio(1);  // insurance if a proj wave shares my SIMD
    f32x2 Wp[32];
    float h = 0.f;
    for (int s = 0; s < SS; ++s) {
      const int p = s & 1;
      // off-chain: W_hh slice + bias(s+2) for the refill
      const float* wr = W_hh + ((size_t)s * HH + lane) * HH;
#pragma unroll
      for (int j = 0; j < 16; ++j) {
        f32x4 v = *(const f32x4*)(wr + 4 * j);
        Wp[2 * j]     = (f32x2){PRE * v.x, PRE * v.y};
        Wp[2 * j + 1] = (f32x2){PRE * v.z, PRE * v.w};
      }
      float nb = 0.f;
      if (s + 2 < SS)
        nb = PRE * (b_ih[(s + 2) * HH + lane] + b_hh[(s + 2) * HH + lane]);

      // wait for all 3 producer slices of segment s
      while (__hip_atomic_load(&prod_cnt[s], __ATOMIC_ACQUIRE,
                               __HIP_MEMORY_SCOPE_WORKGROUP) < 3)
        __builtin_amdgcn_s_sleep(1);

      // ---- 100 steps (R13-proven body; xv from LDS)
      for (int c4 = 0; c4 < 25; ++c4) {
#pragma unroll
        for (int u = 0; u < 4; ++u) {
          const int c = c4 * 4 + u;
          const float* hb = (c == 0) ? hrow : &buf[p][c - 1][0];
          const float xv = buf[p][c][lane];
          f32x2 acc0 = {xv, 0.f};
          f32x2 acc1 = {0.f, 0.f};
#pragma unroll
          for (int j4 = 0; j4 < 16; ++j4) {
            const f32x4 hv = *(const f32x4*)(hb + 4 * j4);
            acc0 = __builtin_elementwise_fma(Wp[2 * j4], lo2(hv), acc0);
            acc1 = __builtin_elementwise_fma(Wp[2 * j4 + 1], hi2(hv), acc1);
          }
          const f32x2 t = acc0 + acc1;
          const float e = __builtin_amdgcn_exp2f(t.x + t.y);  // exp(2z)
          h = 1.f - 2.f * __builtin_amdgcn_rcpf(e + 1.f);
          buf[p][c][lane] = h;  // xp slot consumed -> becomes hist
        }
      }
      hrow[lane] = h;  // handoff for next segment's c=0 broadcast

      // ---- fused head: lane l -> y[b, s*CC + l]
      const float fb = fc_b[s];
      const float* fw = fc_w + s * HH;  // wave-uniform
#pragma unroll
      for (int base = 0; base < CC; base += 64) {
        const int l = base + lane;
        if (l < CC) {
          float z = fb;
#pragma unroll
          for (int i = 0; i < 64; i += 4) {
            const f32x4 hv = *(const f32x4*)&buf[p][l][i];
            z += hv.x * fw[i] + hv.y * fw[i + 1] + hv.z * fw[i + 2] +
                 hv.w * fw[i + 3];
          }
          y[(size_t)b * TT + s * CC + l] =
              __builtin_amdgcn_rcpf(1.f + __expf(-z));
        }
      }

      // ---- refill parity p with bias(s+2), then release to producers
      if (s + 2 < SS) {
#pragma unroll 4
        for (int c = 0; c < CC; ++c) buf[p][c][lane] = nb;
      }
      __threadfence_block();
      __hip_atomic_store(&rec_done[s], 1, __ATOMIC_RELEASE,
                         __HIP_MEMORY_SCOPE_WORKGROUP);
    }
  } else if (w == 1) {
    proj_wave<22, 0>(x, W_ih, buf, prod_cnt, rec_done, b, lane);
  } else if (w == 2) {
    proj_wave<22, 88>(x, W_ih, buf, prod_cnt, rec_done, b, lane);
  } else {
    proj_wave<20, 176>(x, W_ih, buf, prod_cnt, rec_done, b, lane);
  }
}

extern "C" void kernel_launch(void* const* d_in, const int* in_sizes, int n_in,
                              void* d_out, int out_size, void* d_ws,
                              size_t ws_size, hipStream_t stream) {
  const float* x    = (const float*)d_in[0];
  const float* W_ih = (const float*)d_in[1];
  const float* W_hh = (const float*)d_in[2];
  const float* b_ih = (const float*)d_in[3];
  const float* b_hh = (const float*)d_in[4];
  const float* fc_w = (const float*)d_in[5];
  const float* fc_b = (const float*)d_in[6];
  float* y = (float*)d_out;

  fused_kernel<<<BB, 256, 0, stream>>>(x, W_ih, W_hh, b_ih, b_hh,
                                       fc_w, fc_b, y);
}

// Round 20
// 693.461 us; speedup vs baseline: 2.0846x; 2.0846x over previous
//
#include <hip/hip_runtime.h>
#include <cstdint>

#define BB 256
#define TT 1000
#define DD 256
#define SS 10
#define HH 64
#define CC 100
// 2*log2(e): accumulate z2' = PRE*z so tanh(z) = 1 - 2/(exp2(z2')+1)
#define PRE 2.885390081777927f

typedef float f32x2 __attribute__((ext_vector_type(2)));
typedef float f32x4 __attribute__((ext_vector_type(4)));

__device__ __forceinline__ f32x2 lo2(f32x4 v) {
  return __builtin_shufflevector(v, v, 0, 1);
}
__device__ __forceinline__ f32x2 hi2(f32x4 v) {
  return __builtin_shufflevector(v, v, 2, 3);
}

typedef const __attribute__((address_space(1))) uint32_t glb_u32;
typedef __attribute__((address_space(3))) uint32_t lds_u32;

// ---------------------------------------------------------------------------
// Producer wave (w=1,2,3): k-slice [KO, KO+4*KQ) of the D=256 dot.
// x staged through a per-wave 16-DEEP LDS ring via global_load_lds
// (lanes 0..KQ-1 move 16B each = the wave's 4*KQ-float slice of row c).
// R19 bug: ring depth 8 with 8-ahead issue -> (c+8)&7 == c&7, the issued
// load targeted the slot being read this iteration (latency race).
// Depth 16 removes collision ((c+8)&15 never in {c..c+7}&15). Issue-first
// then vmcnt(8): outstanding = rows c..c+8 = 9, so vmcnt(8) completes row c;
// older stray loads (Wk) only deepen the drain -- counted waits can't
// under-wait the oldest. Tail: one vmcnt(0) at c=92, then all resident.
// LDS dest via proper generic->AS(3) addrspacecast (not int truncation).
// Compute: uniform ds_read_b128 (broadcast) + pk_fma; partials into
// bias-pre-initialized buf rows via ds_add_f32. Publish: threadfence_block,
// lane 0 bumps prod_cnt[s]. Segment s writable only after rec_done[s-2].
// ---------------------------------------------------------------------------
template <int KQ, int KO>
__device__ __forceinline__ void proj_wave(
    const float* __restrict__ x, const float* __restrict__ W_ih,
    float (*__restrict__ buf)[CC][68], float (*__restrict__ ring)[4 * KQ],
    int* __restrict__ prod_cnt, int* __restrict__ rec_done, int b, int lane) {
  f32x4 Wk[KQ];
  for (int s = 0; s < SS; ++s) {
    const float* wrow = W_ih + ((size_t)s * HH + lane) * DD + KO;
#pragma unroll
    for (int q = 0; q < KQ; ++q) {
      f32x4 v = *(const f32x4*)(wrow + 4 * q);
      Wk[q] = (f32x4){PRE * v.x, PRE * v.y, PRE * v.z, PRE * v.w};
    }
    if (s >= 2) {
      while (__hip_atomic_load(&rec_done[s - 2], __ATOMIC_ACQUIRE,
                               __HIP_MEMORY_SCOPE_WORKGROUP) == 0)
        __builtin_amdgcn_s_sleep(1);
    }
    float(*dst)[68] = buf[s & 1];
    const char* xbase =
        (const char*)(x + ((size_t)b * TT + (size_t)s * CC) * DD + KO);

    // prologue: stage rows 0..7 (one gl_lds per row, lanes 0..KQ-1 active)
#pragma unroll
    for (int r = 0; r < 8; ++r) {
      if (lane < KQ)
        __builtin_amdgcn_global_load_lds(
            (glb_u32*)(xbase + (size_t)r * (DD * 4) + lane * 16),
            (lds_u32*)&ring[r][0], 16, 0, 0);
    }

    for (int c = 0; c < CC; ++c) {
      if (c + 8 < CC) {
        if (lane < KQ)
          __builtin_amdgcn_global_load_lds(
              (glb_u32*)(xbase + (size_t)(c + 8) * (DD * 4) + lane * 16),
              (lds_u32*)&ring[(c + 8) & 15][0], 16, 0, 0);
        asm volatile("s_waitcnt vmcnt(8)" ::: "memory");
        __builtin_amdgcn_sched_barrier(0);
      } else if (c + 8 == CC) {
        asm volatile("s_waitcnt vmcnt(0)" ::: "memory");
        __builtin_amdgcn_sched_barrier(0);
      }
      const float* xr = &ring[c & 15][0];
      f32x2 a0 = {0.f, 0.f}, a1 = {0.f, 0.f};
#pragma unroll
      for (int q = 0; q < KQ; ++q) {
        const f32x4 v = *(const f32x4*)(xr + 4 * q);
        a0 = __builtin_elementwise_fma(lo2(Wk[q]), lo2(v), a0);
        a1 = __builtin_elementwise_fma(hi2(Wk[q]), hi2(v), a1);
      }
      const f32x2 t = a0 + a1;
      atomicAdd(&dst[c][lane], t.x + t.y);  // ds_add_f32
    }
    __threadfence_block();                      // drain this wave's ds_adds
    if (lane == 0) atomicAdd(&prod_cnt[s], 1);  // publish once per wave
  }
}

// ---------------------------------------------------------------------------
// Fused kernel: 256 blocks x 4 waves = 1 wave per SIMD (no slot sharing).
// Wave 0: R13-proven recurrence + head (xv from LDS). Waves 1-3: proj
// k-slices {88,88,80} with the 16-deep gl_lds ring. Sync: LDS flags +
// s_sleep spin, 2-segment pipeline depth; NO barriers in the main loop.
// buf[2][100][68]: row c of parity s&1 holds xp (bias-init + 3 ds_adds),
// overwritten in place by h at step c; head reads h rows; rec refills parity
// rows with bias(s+2) before releasing them to producers via rec_done[s].
// ---------------------------------------------------------------------------
__global__ __launch_bounds__(256, 1) void fused_kernel(
    const float* __restrict__ x, const float* __restrict__ W_ih,
    const float* __restrict__ W_hh, const float* __restrict__ b_ih,
    const float* __restrict__ b_hh, const float* __restrict__ fc_w,
    const float* __restrict__ fc_b, float* __restrict__ y) {
  __shared__ float buf[2][CC][68];
  __shared__ float hrow[HH];
  __shared__ float ring1[16][88];
  __shared__ float ring2[16][88];
  __shared__ float ring3[16][80];
  __shared__ int prod_cnt[SS];
  __shared__ int rec_done[SS];
  const int b = blockIdx.x;
  const int tid = threadIdx.x;
  const int lane = tid & 63;
  const int w = tid >> 6;

  // ---- prologue: flags, handoff row, bias-init parities 0 and 1
  if (tid < SS) { prod_cnt[tid] = 0; rec_done[tid] = 0; }
  if (tid < HH) hrow[tid] = 0.f;
  {
    const float bias0 = PRE * (b_ih[0 * HH + lane] + b_hh[0 * HH + lane]);
    const float bias1 = PRE * (b_ih[1 * HH + lane] + b_hh[1 * HH + lane]);
    for (int c = w; c < CC; c += 4) {
      buf[0][c][lane] = bias0;
      buf[1][c][lane] = bias1;
    }
  }
  __syncthreads();  // the only block-wide barrier

  if (w == 0) {
    __builtin_amdgcn_s_setprio(1);
    f32x2 Wp[32];
    float h = 0.f;
    for (int s = 0; s < SS; ++s) {
      const int p = s & 1;
      const float* wr = W_hh + ((size_t)s * HH + lane) * HH;
#pragma unroll
      for (int j = 0; j < 16; ++j) {
        f32x4 v = *(const f32x4*)(wr + 4 * j);
        Wp[2 * j]     = (f32x2){PRE * v.x, PRE * v.y};
        Wp[2 * j + 1] = (f32x2){PRE * v.z, PRE * v.w};
      }
      float nb = 0.f;
      if (s + 2 < SS)
        nb = PRE * (b_ih[(s + 2) * HH + lane] + b_hh[(s + 2) * HH + lane]);

      while (__hip_atomic_load(&prod_cnt[s], __ATOMIC_ACQUIRE,
                               __HIP_MEMORY_SCOPE_WORKGROUP) < 3)
        __builtin_amdgcn_s_sleep(1);

      // ---- 100 steps (R13-proven body; xv from LDS)
      for (int c4 = 0; c4 < 25; ++c4) {
#pragma unroll
        for (int u = 0; u < 4; ++u) {
          const int c = c4 * 4 + u;
          const float* hb = (c == 0) ? hrow : &buf[p][c - 1][0];
          const float xv = buf[p][c][lane];
          f32x2 acc0 = {xv, 0.f};
          f32x2 acc1 = {0.f, 0.f};
#pragma unroll
          for (int j4 = 0; j4 < 16; ++j4) {
            const f32x4 hv = *(const f32x4*)(hb + 4 * j4);
            acc0 = __builtin_elementwise_fma(Wp[2 * j4], lo2(hv), acc0);
            acc1 = __builtin_elementwise_fma(Wp[2 * j4 + 1], hi2(hv), acc1);
          }
          const f32x2 t = acc0 + acc1;
          const float e = __builtin_amdgcn_exp2f(t.x + t.y);  // exp(2z)
          h = 1.f - 2.f * __builtin_amdgcn_rcpf(e + 1.f);
          buf[p][c][lane] = h;  // xp slot consumed -> becomes hist
        }
      }
      hrow[lane] = h;

      // ---- fused head: lane l -> y[b, s*CC + l]
      const float fb = fc_b[s];
      const float* fw = fc_w + s * HH;
#pragma unroll
      for (int base = 0; base < CC; base += 64) {
        const int l = base + lane;
        if (l < CC) {
          float z = fb;
#pragma unroll
          for (int i = 0; i < 64; i += 4) {
            const f32x4 hv = *(const f32x4*)&buf[p][l][i];
            z += hv.x * fw[i] + hv.y * fw[i + 1] + hv.z * fw[i + 2] +
                 hv.w * fw[i + 3];
          }
          y[(size_t)b * TT + s * CC + l] =
              __builtin_amdgcn_rcpf(1.f + __expf(-z));
        }
      }

      // ---- refill parity p with bias(s+2), release to producers
      if (s + 2 < SS) {
#pragma unroll 4
        for (int c = 0; c < CC; ++c) buf[p][c][lane] = nb;
      }
      __threadfence_block();
      __hip_atomic_store(&rec_done[s], 1, __ATOMIC_RELEASE,
                         __HIP_MEMORY_SCOPE_WORKGROUP);
    }
  } else if (w == 1) {
    proj_wave<22, 0>(x, W_ih, buf, ring1, prod_cnt, rec_done, b, lane);
  } else if (w == 2) {
    proj_wave<22, 88>(x, W_ih, buf, ring2, prod_cnt, rec_done, b, lane);
  } else {
    proj_wave<20, 176>(x, W_ih, buf, ring3, prod_cnt, rec_done, b, lane);
  }
}

extern "C" void kernel_launch(void* const* d_in, const int* in_sizes, int n_in,
                              void* d_out, int out_size, void* d_ws,
                              size_t ws_size, hipStream_t stream) {
  const float* x    = (const float*)d_in[0];
  const float* W_ih = (const float*)d_in[1];
  const float* W_hh = (const float*)d_in[2];
  const float* b_ih = (const float*)d_in[3];
  const float* b_hh = (const float*)d_in[4];
  const float* fc_w = (const float*)d_in[5];
  const float* fc_b = (const float*)d_in[6];
  float* y = (float*)d_out;

  fused_kernel<<<BB, 256, 0, stream>>>(x, W_ih, W_hh, b_ih, b_hh,
                                       fc_w, fc_b, y);
}

// Round 21
// 314.356 us; speedup vs baseline: 4.5986x; 2.2060x over previous
//
#include <hip/hip_runtime.h>
#include <cstdint>

#define BB 256
#define TT 1000
#define DD 256
#define SS 10
#define HH 64
#define CC 100
// 2*log2(e): accumulate z2' = PRE*z so tanh(z) = 1 - 2/(exp2(z2')+1)
#define PRE 2.885390081777927f

typedef float f32x2 __attribute__((ext_vector_type(2)));
typedef float f32x4 __attribute__((ext_vector_type(4)));

__device__ __forceinline__ f32x2 lo2(f32x4 v) {
  return __builtin_shufflevector(v, v, 0, 1);
}
__device__ __forceinline__ f32x2 hi2(f32x4 v) {
  return __builtin_shufflevector(v, v, 2, 3);
}

// ---------------------------------------------------------------------------
// Kernel 1: input projection  xp[b,t,h] = PRE*(x . W_ih + b_ih + b_hh)
// R16-proven (~106 us): Bs XOR-swizzle kills the 8-way read conflict that
// had been present since R0; pk_fma inner loop halves FMA issue slots.
// ---------------------------------------------------------------------------
__global__ __launch_bounds__(256) void proj_kernel(
    const float* __restrict__ x, const float* __restrict__ W_ih,
    const float* __restrict__ b_ih, const float* __restrict__ b_hh,
    float* __restrict__ xp) {
  __shared__ float As[64][68];
  __shared__ float Bs[64][68];
  const int s = blockIdx.y;
  const int r0 = blockIdx.x * 64;
  const int tid = threadIdx.x;
  const int ty = tid >> 4, tx = tid & 15;
  const int ty4 = ty * 4, tx4 = tx * 4;
  const int bswz = (tx & 7) << 2;  // read-side col XOR (== ((row>>2)&7)<<2)
  f32x2 acc2[4][4];
#pragma unroll
  for (int i = 0; i < 4; ++i)
#pragma unroll
    for (int j = 0; j < 4; ++j) acc2[i][j] = (f32x2){0.f, 0.f};

  for (int kc = 0; kc < 4; ++kc) {
#pragma unroll
    for (int m = 0; m < 4; ++m) {
      int f = m * 256 + tid;
      int row = f >> 4, kq = f & 15;
      int r = r0 + row;
      int b = r / CC, c = r - b * CC;
      const float4 av = *(const float4*)(
          x + ((size_t)b * TT + s * CC + c) * DD + kc * 64 + kq * 4);
      *(float4*)&As[row][kq * 4] = av;
      const float4 wv = *(const float4*)(
          W_ih + ((size_t)s * HH + row) * DD + kc * 64 + kq * 4);
      *(float4*)&Bs[row][(kq * 4) ^ (((row >> 2) & 7) << 2)] = wv;
    }
    __syncthreads();
#pragma unroll 4
    for (int k = 0; k < 64; k += 4) {
      const int kx = k ^ bswz;
      f32x4 a[4], w[4];
#pragma unroll
      for (int i = 0; i < 4; ++i) a[i] = *(const f32x4*)&As[ty4 + i][k];
#pragma unroll
      for (int j = 0; j < 4; ++j) w[j] = *(const f32x4*)&Bs[tx4 + j][kx];
#pragma unroll
      for (int i = 0; i < 4; ++i)
#pragma unroll
        for (int j = 0; j < 4; ++j) {
          acc2[i][j] = __builtin_elementwise_fma(lo2(a[i]), lo2(w[j]), acc2[i][j]);
          acc2[i][j] = __builtin_elementwise_fma(hi2(a[i]), hi2(w[j]), acc2[i][j]);
        }
    }
    __syncthreads();
  }

  const float4 b1 = *(const float4*)(b_ih + s * HH + tx4);
  const float4 b2 = *(const float4*)(b_hh + s * HH + tx4);
#pragma unroll
  for (int i = 0; i < 4; ++i) {
    int r = r0 + ty4 + i;
    int b = r / CC, c = r - b * CC;
    float4 o;
    o.x = PRE * ((acc2[i][0].x + acc2[i][0].y) + b1.x + b2.x);
    o.y = PRE * ((acc2[i][1].x + acc2[i][1].y) + b1.y + b2.y);
    o.z = PRE * ((acc2[i][2].x + acc2[i][2].y) + b1.z + b2.z);
    o.w = PRE * ((acc2[i][3].x + acc2[i][3].y) + b1.w + b2.w);
    *(float4*)(xp + ((size_t)b * TT + s * CC + c) * HH + tx4) = o;
  }
}

// ---------------------------------------------------------------------------
// Kernel 2: recurrence + fused head (R13-proven, ~205 us). Single wave per
// b; 16 ds_read_b128 broadcast + 32 v_pk_fma_f32 per step; exp2-prescaled
// tanh; 4-deep xp ring; per-segment fused head. At the measured ~740 MHz
// low-occupancy clock this is the single-wave slot floor (~76 slots/step);
// K-split (R11/12) and producer/consumer overlap (R14/15/18/20) all lost.
// ---------------------------------------------------------------------------
__global__ __launch_bounds__(64, 1) void rnn_kernel(
    const float* __restrict__ xp, const float* __restrict__ W_hh,
    const float* __restrict__ fc_w, const float* __restrict__ fc_b,
    float* __restrict__ y) {
  __shared__ float hist[CC][68];
  const int b = blockIdx.x;
  const int lane = threadIdx.x;
  hist[CC - 1][lane] = 0.f;  // h0 = 0, read via cp at s=0,c=0

  f32x2 Wp[32];
  float h = 0.f;
  for (int s = 0; s < SS; ++s) {
    const float* wr = W_hh + ((size_t)s * HH + lane) * HH;
#pragma unroll
    for (int j = 0; j < 16; ++j) {
      float4 v = *(const float4*)(wr + 4 * j);
      Wp[2 * j]     = (f32x2){PRE * v.x, PRE * v.y};
      Wp[2 * j + 1] = (f32x2){PRE * v.z, PRE * v.w};
    }
    const float* xps = xp + ((size_t)b * TT + s * CC) * HH + lane;

    float xq0 = xps[0 * HH];
    float xq1 = xps[1 * HH];
    float xq2 = xps[2 * HH];
    float xq3 = xps[3 * HH];

    for (int c4 = 0; c4 < 25; ++c4) {
#pragma unroll
      for (int u = 0; u < 4; ++u) {
        const int c = c4 * 4 + u;
        const int cp = (c == 0) ? CC - 1 : c - 1;
        const float xv = (u == 0) ? xq0 : (u == 1) ? xq1 : (u == 2) ? xq2 : xq3;
        f32x2 acc0 = {xv, 0.f};
        f32x2 acc1 = {0.f, 0.f};
#pragma unroll
        for (int j4 = 0; j4 < 16; ++j4) {
          const f32x4 hv = *(const f32x4*)&hist[cp][j4 * 4];
          acc0 = __builtin_elementwise_fma(Wp[2 * j4], lo2(hv), acc0);
          acc1 = __builtin_elementwise_fma(Wp[2 * j4 + 1], hi2(hv), acc1);
        }
        const f32x2 t = acc0 + acc1;
        const float z2 = t.x + t.y;          // = PRE * z
        const float e = __builtin_amdgcn_exp2f(z2);
        h = 1.f - 2.f * __builtin_amdgcn_rcpf(e + 1.f);
        hist[c][lane] = h;
        if (c4 < 24) {
          const float xn = xps[(c + 4) * HH];
          if (u == 0) xq0 = xn;
          else if (u == 1) xq1 = xn;
          else if (u == 2) xq2 = xn;
          else xq3 = xn;
        }
      }
    }

    // fused head for this segment: lane l -> y[b, s*CC + l]
    const float fb = fc_b[s];
    const float* fw = fc_w + s * HH;  // wave-uniform
#pragma unroll
    for (int base = 0; base < CC; base += 64) {
      int l = base + lane;
      if (l < CC) {
        float z = fb;
#pragma unroll
        for (int i = 0; i < 64; i += 4) {
          const float4 hv = *(const float4*)&hist[l][i];
          z += hv.x * fw[i] + hv.y * fw[i + 1] + hv.z * fw[i + 2] +
               hv.w * fw[i + 3];
        }
        y[(size_t)b * TT + s * CC + l] =
            __builtin_amdgcn_rcpf(1.f + __expf(-z));
      }
    }
  }
}

extern "C" void kernel_launch(void* const* d_in, const int* in_sizes, int n_in,
                              void* d_out, int out_size, void* d_ws,
                              size_t ws_size, hipStream_t stream) {
  const float* x    = (const float*)d_in[0];
  const float* W_ih = (const float*)d_in[1];
  const float* W_hh = (const float*)d_in[2];
  const float* b_ih = (const float*)d_in[3];
  const float* b_hh = (const float*)d_in[4];
  const float* fc_w = (const float*)d_in[5];
  const float* fc_b = (const float*)d_in[6];
  float* y  = (float*)d_out;
  float* xp = (float*)d_ws;  // [B][T][H] fp32 = 65.5 MB

  proj_kernel<<<dim3(400, 10), 256, 0, stream>>>(x, W_ih, b_ih, b_hh, xp);
  rnn_kernel<<<256, 64, 0, stream>>>(xp, W_hh, fc_w, fc_b, y);
}